// Round 2
// baseline (443.645 us; speedup 1.0000x reference)
//
#include <hip/hip_runtime.h>

// out[b,s,f] = sx[b,s] * sk[f] * sum_d qx[b,s,d] * qk[d,f]
// Exact int32 accumulation via v_mfma_i32_16x16x64_i8.
//
// R4:
//  * GEMM + global tile layout reverted EXACTLY to R2 (monotone staging
//    reads; 137.6 us, MfmaUtil 46%). R3 proved global_load_lds needs
//    monotone lane->address mapping: lane-permuted 1KB reads cost +30us.
//  * Producer side restructured instead:
//      - amax pass (fused W-partials + X row-amax) writes sx/sxinv only.
//      - act_quant: one block per 16-row A-tile, re-reads X (L3-resident),
//        writes the 64KB tile with complete 64B sectors from ONE block
//        (kills the cross-XCD partial-line RMW of the R0/R2 producer).
//      - wk_quant: R2 output layout, float4 W reads, inline scale-combine.

#define M_DIM 8192
#define K_DIM 4096
#define N_DIM 4096

typedef int v4i __attribute__((ext_vector_type(4)));
typedef __attribute__((address_space(3))) void lds_void_t;
typedef const __attribute__((address_space(1))) void g_void_t;

// ---------------- pass 1: W column-amax partials (blocks 0..127) +
//                  X row-amax -> sx, sxinv (blocks 128..1151, 8 rows each) ----
__global__ void amax_pass(const float* __restrict__ X,
                          float* __restrict__ sx, float* __restrict__ sxinv,
                          const float* __restrict__ W,
                          float* __restrict__ part) {
  const int t = threadIdx.x;

  if (blockIdx.x < 128) {
    // per-column |max| over a 128-row slab of W, float4-wide.
    const int f4 = (blockIdx.x & 3) * 256 + t;  // float4 column 0..1023
    const int slab = blockIdx.x >> 2;           // 0..31
    const float4* p = (const float4*)W + (size_t)slab * 128 * 1024 + f4;
    float4 a0 = {0.f, 0.f, 0.f, 0.f}, a1 = {0.f, 0.f, 0.f, 0.f};
#pragma unroll 8
    for (int i = 0; i < 64; ++i) {
      float4 u = p[(size_t)(2 * i) * 1024];
      float4 v = p[(size_t)(2 * i + 1) * 1024];
      a0.x = fmaxf(a0.x, fabsf(u.x));
      a0.y = fmaxf(a0.y, fabsf(u.y));
      a0.z = fmaxf(a0.z, fabsf(u.z));
      a0.w = fmaxf(a0.w, fabsf(u.w));
      a1.x = fmaxf(a1.x, fabsf(v.x));
      a1.y = fmaxf(a1.y, fabsf(v.y));
      a1.z = fmaxf(a1.z, fabsf(v.z));
      a1.w = fmaxf(a1.w, fabsf(v.w));
    }
    float4 r;
    r.x = fmaxf(a0.x, a1.x);
    r.y = fmaxf(a0.y, a1.y);
    r.z = fmaxf(a0.z, a1.z);
    r.w = fmaxf(a0.w, a1.w);
    ((float4*)part)[(size_t)slab * 1024 + f4] = r;
    return;
  }

  // ---- X row-amax: 8 rows per block, 32 lanes per row ----
  const int row = (blockIdx.x - 128) * 8 + (t >> 5);
  const int j = t & 31;
  const float4* xr = (const float4*)X + (size_t)row * 1024;
  float am = 0.f;
#pragma unroll 8
  for (int i = 0; i < 32; ++i) {
    float4 v = xr[j + 32 * i];  // 512B contiguous per 32-lane group
    am = fmaxf(am, fmaxf(fmaxf(fabsf(v.x), fabsf(v.y)),
                         fmaxf(fabsf(v.z), fabsf(v.w))));
  }
#pragma unroll
  for (int off = 16; off > 0; off >>= 1)
    am = fmaxf(am, __shfl_down(am, off, 32));
  if (j == 0) {
    float scale = fmaxf(am, 1e-6f) / 127.0f;  // matches ref
    sx[row] = scale;
    sxinv[row] = 1.0f / scale;
  }
}

// ---------------- pass 2: activation quant into R2-layout tiles ----------------
// Block = one 16-row tile (64KB out). thread t: row=t>>4, j=t&15.
// Iteration u: thread owns k-slice s=u*16+j -> reads 64B of X, writes one
// 16B chunk. Per wave-instr: reads 1KB contiguous x4; writes 16 complete
// 64B sectors (rows t>>4 within a wave form a row-quad).
__global__ void act_quant(const float* __restrict__ X,
                          const float* __restrict__ sxinv,
                          signed char* __restrict__ At) {
  const int t = threadIdx.x;
  const int row = t >> 4;  // 0..15
  const int j = t & 15;
  const int r0 = blockIdx.x * 16;
  const float inv = sxinv[r0 + row];
  const float4* xr = (const float4*)X + (size_t)(r0 + row) * 1024;
  signed char* tile = At + (size_t)blockIdx.x * 65536 + row * 16;
#pragma unroll 4
  for (int u = 0; u < 16; ++u) {
    const int s = u * 16 + j;  // 16B k-slice index 0..255
    unsigned int d[4];
#pragma unroll
    for (int c = 0; c < 4; ++c) {
      float4 v = xr[s * 4 + c];
      int q0 = (int)fminf(fmaxf(rintf(v.x * inv), -127.f), 127.f);
      int q1 = (int)fminf(fmaxf(rintf(v.y * inv), -127.f), 127.f);
      int q2 = (int)fminf(fmaxf(rintf(v.z * inv), -127.f), 127.f);
      int q3 = (int)fminf(fmaxf(rintf(v.w * inv), -127.f), 127.f);
      d[c] = (q0 & 255) | ((q1 & 255) << 8) | ((q2 & 255) << 16) | (q3 << 24);
    }
    v4i w = {(int)d[0], (int)d[1], (int)d[2], (int)d[3]};
    *(v4i*)(tile + s * 256) = w;  // [ks][row][16B]
  }
}

// ---------------- weight quant (+ inline scale combine) into Bt (R2 layout) ----
__global__ void wk_quant(const float* __restrict__ W,
                         const float* __restrict__ part,
                         signed char* __restrict__ Bt,
                         float* __restrict__ sk) {
  const int bx = blockIdx.x;
  const int f0 = (bx & 63) * 64;
  const int d0 = (bx >> 6) * 64;
  const int t = threadIdx.x;
  const int fl4 = t & 15;   // float4-column within the 64-f stripe
  const int dl0 = t >> 4;   // row group 0..15
  __shared__ __align__(16) signed char tile[64 * 80];  // [f_local][d], stride 80
  __shared__ float sl_inv[64];

  // issue the big W loads first; the scale-combine hides under them
  float4 wv[4];
#pragma unroll
  for (int c = 0; c < 4; ++c) {
    const int dl = c * 16 + dl0;
    wv[c] = ((const float4*)W)[(size_t)(d0 + dl) * 1024 + (f0 >> 2) + fl4];
  }
  // combine 32 slab partials -> per-column scale (threads 0..63)
  if (t < 64) {
    const int f = f0 + t;
    float m = 0.f;
#pragma unroll
    for (int s = 0; s < 32; ++s) m = fmaxf(m, part[(size_t)s * 4096 + f]);
    const float scale = fmaxf(m, 1e-6f) / 127.0f;
    if (bx < 64) sk[f] = scale;  // d0==0 blocks publish sk exactly once
    sl_inv[t] = 1.0f / scale;
  }
  __syncthreads();
  const float4 inv4 = *(const float4*)&sl_inv[fl4 * 4];
#pragma unroll
  for (int c = 0; c < 4; ++c) {
    const int dl = c * 16 + dl0;
    tile[(fl4 * 4 + 0) * 80 + dl] =
        (signed char)(int)fminf(fmaxf(rintf(wv[c].x * inv4.x), -127.f), 127.f);
    tile[(fl4 * 4 + 1) * 80 + dl] =
        (signed char)(int)fminf(fmaxf(rintf(wv[c].y * inv4.y), -127.f), 127.f);
    tile[(fl4 * 4 + 2) * 80 + dl] =
        (signed char)(int)fminf(fmaxf(rintf(wv[c].z * inv4.z), -127.f), 127.f);
    tile[(fl4 * 4 + 3) * 80 + dl] =
        (signed char)(int)fminf(fmaxf(rintf(wv[c].w * inv4.w), -127.f), 127.f);
  }
  __syncthreads();
  // one 16B chunk per thread; R2 layout: [f>>4][ks=d>>4][f&15][16B]
  const int frow = t >> 2;
  const int ksl = t & 3;
  v4i w = *(const v4i*)&tile[frow * 80 + ksl * 16];
  const int f = f0 + frow;
  signed char* dst = Bt + (size_t)(f >> 4) * 65536 + ((d0 >> 4) + ksl) * 256 +
                     (f & 15) * 16;
  *(v4i*)dst = w;
}

// ---------------- int8 GEMM: exact R2 kernel (137.6us, MfmaUtil 46%) ----------
__global__ __launch_bounds__(256, 2) void gemm_i8(
    const signed char* __restrict__ At, const signed char* __restrict__ Bt,
    const float* __restrict__ sx, const float* __restrict__ sk,
    float* __restrict__ C) {
  const int n0 = blockIdx.x * 128;
  const int m0 = blockIdx.y * 128;
  const int t = threadIdx.x;
  const int lane = t & 63;
  const int wave = t >> 6;
  const int wm = (wave >> 1) * 64;  // wave's 64x64 sub-tile
  const int wn = (wave & 1) * 64;
  const int lrow = lane & 15;
  const int lq = lane >> 4;

  __shared__ __align__(16) signed char lds[32768];
  signed char* lA = lds;
  signed char* lB = lds + 16384;

  v4i acc[4][4];
#pragma unroll
  for (int i = 0; i < 4; ++i)
#pragma unroll
    for (int j = 0; j < 4; ++j) acc[i][j] = (v4i){0, 0, 0, 0};

  const signed char* Abase = At + (size_t)(m0 >> 4) * 65536;
  const signed char* Bbase = Bt + (size_t)(n0 >> 4) * 65536;

  // fragment read bases: addr = mt_i*2048 + s*1024 + lane*16 (contiguous)
  const int la = ((wave >> 1) * 4) * 2048 + lane * 16;
  const int lb = ((wave & 1) * 4) * 2048 + lane * 16;

  for (int kb = 0; kb < K_DIM; kb += 128) {
    const int kofs = kb * 16;  // (kb/16)*256 bytes into each tile-row
    // stage 16KB A + 16KB B: every wave-instr reads 1KB contiguous,
    // MONOTONE lane->address (identity copy of the fragment-tiled layout)
#pragma unroll
    for (int j = 0; j < 4; ++j) {
      const int c = j * 256 + t;
      const int mt_i = c >> 7;
      const int inner = c & 127;
      __builtin_amdgcn_global_load_lds(
          (g_void_t*)(Abase + (size_t)mt_i * 65536 + kofs + inner * 16),
          (lds_void_t*)(lA + c * 16), 16, 0, 0);
      __builtin_amdgcn_global_load_lds(
          (g_void_t*)(Bbase + (size_t)mt_i * 65536 + kofs + inner * 16),
          (lds_void_t*)(lB + c * 16), 16, 0, 0);
    }
    __syncthreads();
#pragma unroll
    for (int s = 0; s < 2; ++s) {  // two K=64 steps per staging round
      v4i af[4], bf[4];
#pragma unroll
      for (int i = 0; i < 4; ++i) af[i] = *(const v4i*)(lA + la + i * 2048 + s * 1024);
#pragma unroll
      for (int i = 0; i < 4; ++i) bf[i] = *(const v4i*)(lB + lb + i * 2048 + s * 1024);
#pragma unroll
      for (int mi = 0; mi < 4; ++mi)
#pragma unroll
        for (int ni = 0; ni < 4; ++ni)
          acc[mi][ni] =
              __builtin_amdgcn_mfma_i32_16x16x64_i8(af[mi], bf[ni], acc[mi][ni], 0, 0, 0);
    }
    __syncthreads();
  }

  // epilogue: C/D layout col=lane&15, row=(lane>>4)*4+reg
#pragma unroll
  for (int mi = 0; mi < 4; ++mi) {
#pragma unroll
    for (int ni = 0; ni < 4; ++ni) {
      const int gn = n0 + wn + ni * 16 + lrow;
      const float skv = sk[gn];
#pragma unroll
      for (int r = 0; r < 4; ++r) {
        const int gm = m0 + wm + mi * 16 + lq * 4 + r;
        C[(size_t)gm * N_DIM + gn] = (float)acc[mi][ni][r] * sx[gm] * skv;
      }
    }
  }
}

// ---------------- launch ----------------
extern "C" void kernel_launch(void* const* d_in, const int* in_sizes, int n_in,
                              void* d_out, int out_size, void* d_ws, size_t ws_size,
                              hipStream_t stream) {
  const float* X = (const float*)d_in[0];  // [4,2048,4096] fp32
  const float* W = (const float*)d_in[1];  // [4096,4096] fp32
  float* out = (float*)d_out;              // [4,2048,4096] fp32
  char* ws = (char*)d_ws;

  signed char* At = (signed char*)ws;               // 32 MB  tiled A
  signed char* Bt = (signed char*)(ws + 33554432);  // 16 MB  tiled B
  float* sx = (float*)(ws + 50331648);              // 32 KB
  float* sxinv = (float*)(ws + 50364416);           // 32 KB
  float* sk = (float*)(ws + 50397184);              // 16 KB
  float* part = (float*)(ws + 50413568);            // 512 KB

  amax_pass<<<1152, 256, 0, stream>>>(X, sx, sxinv, W, part);
  act_quant<<<512, 256, 0, stream>>>(X, sxinv, At);
  wk_quant<<<4096, 256, 0, stream>>>(W, part, Bt, sk);
  gemm_i8<<<dim3(N_DIM / 128, M_DIM / 128), 256, 0, stream>>>(At, Bt, sx, sk, out);
}

// Round 3
// 440.421 us; speedup vs baseline: 1.0073x; 1.0073x over previous
//
#include <hip/hip_runtime.h>

// out[b,s,f] = sx[b,s] * sk[f] * sum_d qx[b,s,d] * qk[d,f]
// Exact int32 accumulation via v_mfma_i32_16x16x64_i8.
//
// R5: 256x256 8-phase GEMM (T3+T4 counted-vmcnt + T5 setprio, per catalog).
//  * 512 thr / 8 waves (2Mx4N), BK=128 bytes, LDS = 2 x (32KB A + 32KB B).
//  * Fragment-tiled layout => LDS reads are lane*16 contiguous: no swizzle
//    (T2) needed, zero bank conflicts by construction.
//  * Global At/Bt: [panel256][pos16][kb32][ksl8][r16][16B] with a position
//    permutation chosen so stage-load j covers exactly one row-half unit:
//      A: pos-quarters = row-quarters {0,2,1,3}  (loads j0,j1 = rows 0-63,128-191
//         = union of both waves' mq=0 frags; j2,j3 = mq=1)
//      B: pos p = nq*8 + (wn>>6)*2 + ni          (j0,j1 = nq=0 strips; j2,j3 = nq=1)
//  * Phase = {issue 2 global_load_lds (tile kt+1); 12 ds_read_b128 (quadrant);
//             s_waitcnt vmcnt(4); s_barrier; setprio(1); 16 MFMA; setprio(0);
//             lgkmcnt(0); s_barrier}.  vmcnt never drains to 0 in steady state.
//    Wait math (per-wave, 8 loads/tile issued 2/phase, order A01,B01,A23,B23):
//      entering tile kt: outstanding = kt.{Aj2,Aj3,Bj2,Bj3} (4)
//      ph1 +2 -> 6, need kt.Aj2,Aj3  -> vmcnt(4)
//      ph2 +2 -> 6, need kt.Bj2,Bj3  -> vmcnt(4)
//      ph3 +2 -> 6, no need
//      ph4 +2 -> 8, need kt+1 first 4 -> vmcnt(4)
//    Last tile peeled: vmcnt(2), vmcnt(0), -, -.
//  * Producers = R4 kernels, destination-address formula only changed.

#define M_DIM 8192
#define K_DIM 4096
#define N_DIM 4096
#define NT (K_DIM / 128)

typedef int v4i __attribute__((ext_vector_type(4)));
typedef __attribute__((address_space(3))) void lds_void_t;
typedef const __attribute__((address_space(1))) void g_void_t;

// ---------------- pass 1: W column-amax partials (blocks 0..127) +
//                  X row-amax -> sx, sxinv (blocks 128..1151, 8 rows each) ----
__global__ void amax_pass(const float* __restrict__ X,
                          float* __restrict__ sx, float* __restrict__ sxinv,
                          const float* __restrict__ W,
                          float* __restrict__ part) {
  const int t = threadIdx.x;

  if (blockIdx.x < 128) {
    const int f4 = (blockIdx.x & 3) * 256 + t;  // float4 column 0..1023
    const int slab = blockIdx.x >> 2;           // 0..31
    const float4* p = (const float4*)W + (size_t)slab * 128 * 1024 + f4;
    float4 a0 = {0.f, 0.f, 0.f, 0.f}, a1 = {0.f, 0.f, 0.f, 0.f};
#pragma unroll 8
    for (int i = 0; i < 64; ++i) {
      float4 u = p[(size_t)(2 * i) * 1024];
      float4 v = p[(size_t)(2 * i + 1) * 1024];
      a0.x = fmaxf(a0.x, fabsf(u.x));
      a0.y = fmaxf(a0.y, fabsf(u.y));
      a0.z = fmaxf(a0.z, fabsf(u.z));
      a0.w = fmaxf(a0.w, fabsf(u.w));
      a1.x = fmaxf(a1.x, fabsf(v.x));
      a1.y = fmaxf(a1.y, fabsf(v.y));
      a1.z = fmaxf(a1.z, fabsf(v.z));
      a1.w = fmaxf(a1.w, fabsf(v.w));
    }
    float4 r;
    r.x = fmaxf(a0.x, a1.x);
    r.y = fmaxf(a0.y, a1.y);
    r.z = fmaxf(a0.z, a1.z);
    r.w = fmaxf(a0.w, a1.w);
    ((float4*)part)[(size_t)slab * 1024 + f4] = r;
    return;
  }

  const int row = (blockIdx.x - 128) * 8 + (t >> 5);
  const int j = t & 31;
  const float4* xr = (const float4*)X + (size_t)row * 1024;
  float am = 0.f;
#pragma unroll 8
  for (int i = 0; i < 32; ++i) {
    float4 v = xr[j + 32 * i];
    am = fmaxf(am, fmaxf(fmaxf(fabsf(v.x), fabsf(v.y)),
                         fmaxf(fabsf(v.z), fabsf(v.w))));
  }
#pragma unroll
  for (int off = 16; off > 0; off >>= 1)
    am = fmaxf(am, __shfl_down(am, off, 32));
  if (j == 0) {
    float scale = fmaxf(am, 1e-6f) / 127.0f;  // matches ref
    sx[row] = scale;
    sxinv[row] = 1.0f / scale;
  }
}

// ---------------- pass 2: activation quant into permuted-panel tiles ---------
// Block = one 16-row tile. dst tile position p within its 256-row panel:
// mt = tile index 0..15, quarter q=mt>>2 permuted {0,2,1,3}.
__global__ void act_quant(const float* __restrict__ X,
                          const float* __restrict__ sxinv,
                          signed char* __restrict__ At) {
  const int t = threadIdx.x;
  const int row = t >> 4;  // 0..15
  const int j = t & 15;
  const int r0 = blockIdx.x * 16;
  const int mt = blockIdx.x & 15;
  const int panel = blockIdx.x >> 4;
  const int q = mt >> 2;
  const int pq = ((q & 1) << 1) | (q >> 1);  // {0,2,1,3}
  const int p = (mt & 3) | (pq << 2);
  const float inv = sxinv[r0 + row];
  const float4* xr = (const float4*)X + (size_t)(r0 + row) * 1024;
  signed char* tile = At + (size_t)panel * 1048576 + (size_t)p * 65536 + row * 16;
#pragma unroll 4
  for (int u = 0; u < 16; ++u) {
    const int s = u * 16 + j;  // 16B k-slice index 0..255
    unsigned int d[4];
#pragma unroll
    for (int c = 0; c < 4; ++c) {
      float4 v = xr[s * 4 + c];
      int q0 = (int)fminf(fmaxf(rintf(v.x * inv), -127.f), 127.f);
      int q1 = (int)fminf(fmaxf(rintf(v.y * inv), -127.f), 127.f);
      int q2 = (int)fminf(fmaxf(rintf(v.z * inv), -127.f), 127.f);
      int q3 = (int)fminf(fmaxf(rintf(v.w * inv), -127.f), 127.f);
      d[c] = (q0 & 255) | ((q1 & 255) << 8) | ((q2 & 255) << 16) | (q3 << 24);
    }
    v4i w = {(int)d[0], (int)d[1], (int)d[2], (int)d[3]};
    *(v4i*)(tile + (s >> 3) * 2048 + (s & 7) * 256) = w;
  }
}

// ---------------- weight quant (+ inline scale combine) into Bt --------------
__global__ void wk_quant(const float* __restrict__ W,
                         const float* __restrict__ part,
                         signed char* __restrict__ Bt,
                         float* __restrict__ sk) {
  const int bx = blockIdx.x;
  const int f0 = (bx & 63) * 64;
  const int d0 = (bx >> 6) * 64;
  const int t = threadIdx.x;
  const int fl4 = t & 15;
  const int dl0 = t >> 4;
  __shared__ __align__(16) signed char tile[64 * 80];
  __shared__ float sl_inv[64];

  float4 wv[4];
#pragma unroll
  for (int c = 0; c < 4; ++c) {
    const int dl = c * 16 + dl0;
    wv[c] = ((const float4*)W)[(size_t)(d0 + dl) * 1024 + (f0 >> 2) + fl4];
  }
  if (t < 64) {
    const int f = f0 + t;
    float m = 0.f;
#pragma unroll
    for (int s = 0; s < 32; ++s) m = fmaxf(m, part[(size_t)s * 4096 + f]);
    const float scale = fmaxf(m, 1e-6f) / 127.0f;
    if (bx < 64) sk[f] = scale;
    sl_inv[t] = 1.0f / scale;
  }
  __syncthreads();
  const float4 inv4 = *(const float4*)&sl_inv[fl4 * 4];
#pragma unroll
  for (int c = 0; c < 4; ++c) {
    const int dl = c * 16 + dl0;
    tile[(fl4 * 4 + 0) * 80 + dl] =
        (signed char)(int)fminf(fmaxf(rintf(wv[c].x * inv4.x), -127.f), 127.f);
    tile[(fl4 * 4 + 1) * 80 + dl] =
        (signed char)(int)fminf(fmaxf(rintf(wv[c].y * inv4.y), -127.f), 127.f);
    tile[(fl4 * 4 + 2) * 80 + dl] =
        (signed char)(int)fminf(fmaxf(rintf(wv[c].z * inv4.z), -127.f), 127.f);
    tile[(fl4 * 4 + 3) * 80 + dl] =
        (signed char)(int)fminf(fmaxf(rintf(wv[c].w * inv4.w), -127.f), 127.f);
  }
  __syncthreads();
  const int frow = t >> 2;
  const int ksl = t & 3;
  v4i w = *(const v4i*)&tile[frow * 80 + ksl * 16];
  const int f = f0 + frow;
  const int lt = (f >> 4) & 15;
  const int p = ((lt >> 1) & 1) * 8 + (lt >> 2) * 2 + (lt & 1);
  const int s = (d0 >> 4) + ksl;  // 16B k-slice index
  signed char* dst = Bt + (size_t)(f >> 8) * 1048576 + (size_t)p * 65536 +
                     (s >> 3) * 2048 + (s & 7) * 256 + (f & 15) * 16;
  *(v4i*)dst = w;
}

// ---------------- int8 GEMM: 256x256, 8 waves, 8-phase counted-vmcnt ---------
#define SA(J, KT, STG)                                                        \
  __builtin_amdgcn_global_load_lds(                                           \
      (g_void_t*)(Ap + soff[J] + (size_t)(KT)*2048),                          \
      (lds_void_t*)((STG) + ((J)*512 + t) * 16), 16, 0, 0)
#define SB(J, KT, STG)                                                        \
  __builtin_amdgcn_global_load_lds(                                           \
      (g_void_t*)(Bp + soff[J] + (size_t)(KT)*2048),                          \
      (lds_void_t*)((STG) + 32768 + ((J)*512 + t) * 16), 16, 0, 0)

#define QPHASE(MQ, NQ, STAGE_STMT, WAIT_STMT)                                 \
  do {                                                                        \
    STAGE_STMT;                                                               \
    v4i af[4][2], bf[2][2];                                                   \
    _Pragma("unroll") for (int i = 0; i < 4; ++i) {                           \
      const signed char* pa = lA + ((MQ)*8 + wam + i) * 2048 + lane * 16;     \
      af[i][0] = *(const v4i*)pa;                                             \
      af[i][1] = *(const v4i*)(pa + 1024);                                    \
    }                                                                         \
    _Pragma("unroll") for (int ni = 0; ni < 2; ++ni) {                        \
      const signed char* pb = lB + ((NQ)*8 + wbn + ni) * 2048 + lane * 16;    \
      bf[ni][0] = *(const v4i*)pb;                                            \
      bf[ni][1] = *(const v4i*)(pb + 1024);                                   \
    }                                                                         \
    WAIT_STMT;                                                                \
    asm volatile("s_barrier" ::: "memory");                                   \
    __builtin_amdgcn_s_setprio(1);                                            \
    _Pragma("unroll") for (int s2 = 0; s2 < 2; ++s2)                          \
        _Pragma("unroll") for (int i = 0; i < 4; ++i)                         \
            _Pragma("unroll") for (int ni = 0; ni < 2; ++ni)                  \
                acc[(MQ)*4 + i][(NQ)*2 + ni] =                                \
        __builtin_amdgcn_mfma_i32_16x16x64_i8(                                \
            af[i][s2], bf[ni][s2], acc[(MQ)*4 + i][(NQ)*2 + ni], 0, 0, 0);    \
    __builtin_amdgcn_s_setprio(0);                                            \
    asm volatile("s_waitcnt lgkmcnt(0)" ::: "memory");                        \
    asm volatile("s_barrier" ::: "memory");                                   \
  } while (0)

#define WAIT4 asm volatile("s_waitcnt vmcnt(4)" ::: "memory")
#define WAIT2 asm volatile("s_waitcnt vmcnt(2)" ::: "memory")
#define WAIT0 asm volatile("s_waitcnt vmcnt(0)" ::: "memory")

__global__ __launch_bounds__(512, 2) void gemm_i8(
    const signed char* __restrict__ At, const signed char* __restrict__ Bt,
    const float* __restrict__ sx, const float* __restrict__ sk,
    float* __restrict__ C) {
  const int n0 = blockIdx.x * 256;
  const int m0 = blockIdx.y * 256;
  const int t = threadIdx.x;
  const int lane = t & 63;
  const int wave = t >> 6;            // 0..7
  const int wm = (wave >> 2) * 128;   // 0 / 128
  const int wn = (wave & 3) * 64;     // 0..192
  const int wam = (wave >> 2) * 4;    // A pos offset for this wave's M-half
  const int wbn = (wave & 3) * 2;     // B pos offset for this wave's N-strip
  const int lrow = lane & 15;
  const int lq = lane >> 4;

  __shared__ __align__(16) signed char lds[131072];  // 2 x (32KB A + 32KB B)

  v4i acc[8][4];
#pragma unroll
  for (int i = 0; i < 8; ++i)
#pragma unroll
    for (int j = 0; j < 4; ++j) acc[i][j] = (v4i){0, 0, 0, 0};

  const signed char* Ap = At + (size_t)(m0 >> 8) * 1048576;
  const signed char* Bp = Bt + (size_t)(n0 >> 8) * 1048576;

  // per-thread stage-source offsets (identical for A and B layouts)
  int soff[4];
#pragma unroll
  for (int j = 0; j < 4; ++j)
    soff[j] = (j * 4 + (t >> 7)) * 65536 + (t & 127) * 16;

  // ---- prologue: stage tile 0 into buf0 in phase order, publish halves 0 ----
  {
    signed char* stg = lds;
    SA(0, 0, stg); SA(1, 0, stg);
    SB(0, 0, stg); SB(1, 0, stg);
    SA(2, 0, stg); SA(3, 0, stg);
    SB(2, 0, stg); SB(3, 0, stg);
  }
  WAIT4;
  asm volatile("s_barrier" ::: "memory");

  // ---- main loop: tiles 0..NT-2, staging tile kt+1 ----
#pragma unroll 1
  for (int kt = 0; kt < NT - 1; ++kt) {
    const signed char* lA = lds + (kt & 1) * 65536;
    const signed char* lB = lA + 32768;
    signed char* stg = lds + (((kt & 1) ^ 1) * 65536);
    const int nx = kt + 1;
    QPHASE(0, 0, { SA(0, nx, stg); SA(1, nx, stg); }, WAIT4);
    QPHASE(1, 0, { SB(0, nx, stg); SB(1, nx, stg); }, WAIT4);
    QPHASE(0, 1, { SA(2, nx, stg); SA(3, nx, stg); }, );
    QPHASE(1, 1, { SB(2, nx, stg); SB(3, nx, stg); }, WAIT4);
  }

  // ---- epilogue tile NT-1: no staging, drain 2 -> 0 ----
  {
    const signed char* lA = lds + ((NT - 1) & 1) * 65536;
    const signed char* lB = lA + 32768;
    QPHASE(0, 0, , WAIT2);
    QPHASE(1, 0, , WAIT0);
    QPHASE(0, 1, , );
    QPHASE(1, 1, , );
  }

  // ---- C write: C/D layout col=lane&15, row=(lane>>4)*4+reg ----
#pragma unroll
  for (int mi = 0; mi < 8; ++mi) {
    const int gmb = m0 + wm + (mi >> 2) * 64 + (mi & 3) * 16 + lq * 4;
#pragma unroll
    for (int ni = 0; ni < 4; ++ni) {
      const int gn = n0 + wn + (ni >> 1) * 32 + (ni & 1) * 16 + lrow;
      const float skv = sk[gn];
#pragma unroll
      for (int r = 0; r < 4; ++r) {
        const int gm = gmb + r;
        C[(size_t)gm * N_DIM + gn] = (float)acc[mi][ni][r] * sx[gm] * skv;
      }
    }
  }
}

// ---------------- launch ----------------
extern "C" void kernel_launch(void* const* d_in, const int* in_sizes, int n_in,
                              void* d_out, int out_size, void* d_ws, size_t ws_size,
                              hipStream_t stream) {
  const float* X = (const float*)d_in[0];  // [4,2048,4096] fp32
  const float* W = (const float*)d_in[1];  // [4096,4096] fp32
  float* out = (float*)d_out;              // [4,2048,4096] fp32
  char* ws = (char*)d_ws;

  signed char* At = (signed char*)ws;               // 32 MB  tiled A
  signed char* Bt = (signed char*)(ws + 33554432);  // 16 MB  tiled B
  float* sx = (float*)(ws + 50331648);              // 32 KB
  float* sxinv = (float*)(ws + 50364416);           // 32 KB
  float* sk = (float*)(ws + 50397184);              // 16 KB
  float* part = (float*)(ws + 50413568);            // 512 KB

  amax_pass<<<1152, 256, 0, stream>>>(X, sx, sxinv, W, part);
  act_quant<<<512, 256, 0, stream>>>(X, sxinv, At);
  wk_quant<<<4096, 256, 0, stream>>>(W, part, Bt, sk);
  gemm_i8<<<dim3(N_DIM / 256, M_DIM / 256), 512, 0, stream>>>(At, Bt, sx, sk, out);
}

// Round 4
// 426.511 us; speedup vs baseline: 1.0402x; 1.0326x over previous
//
#include <hip/hip_runtime.h>

// out[b,s,f] = sx[b,s] * sk[f] * sum_d qx[b,s,d] * qk[d,f]
// Exact int32 accumulation via v_mfma_i32_16x16x64_i8.
//
// R6:
//  * GEMM: exact R2 kernel (proven 137.6us / MfmaUtil 46%). R5's 8-phase
//    port regressed (171us, MfmaUtil 34%): 3 vmcnt waits/K-tile at 1-tile
//    prefetch depth + 2x redundant quadrant ds_reads + 1 block/CU. Reverted.
//  * Activation path = ONE dispatch reading X exactly once:
//    block = 16-row tile, 1024 thr, wave==row. amax over 16 float4 held in
//    registers, wave shfl-reduce + broadcast, quantize from registers,
//    write R2-layout tile (block writes full 128B lines -> no RMW).
//  * W-slab partial amax fused into same dispatch (blocks 0..31, float4).
//  * wk_quant: R4 version (inline scale combine, publishes sk, R2 layout).
//  Purpose: discriminate prep-kernel-bound (total -> ~300) vs structural
//  overhead (non-gemm stays ~270) with the GEMM control restored.

#define M_DIM 8192
#define K_DIM 4096
#define N_DIM 4096

typedef int v4i __attribute__((ext_vector_type(4)));
typedef __attribute__((address_space(3))) void lds_void_t;
typedef const __attribute__((address_space(1))) void g_void_t;

// ---------------- pass 1: W-slab amax partials (blocks 0..31) +
//                  fused act row-amax + quant (blocks 32..543) ----------------
__global__ __launch_bounds__(1024) void fused_prep(
    const float* __restrict__ X, const float* __restrict__ W,
    signed char* __restrict__ At, float* __restrict__ sx,
    float* __restrict__ part) {
  const int t = threadIdx.x;

  if (blockIdx.x < 32) {
    // per-column |max| over a 128-row slab of W; t = float4-column 0..1023
    const int slab = blockIdx.x;
    const float4* p = (const float4*)W + (size_t)slab * 128 * 1024 + t;
    float4 a = {0.f, 0.f, 0.f, 0.f};
#pragma unroll 8
    for (int i = 0; i < 128; ++i) {
      float4 u = p[(size_t)i * 1024];
      a.x = fmaxf(a.x, fabsf(u.x));
      a.y = fmaxf(a.y, fabsf(u.y));
      a.z = fmaxf(a.z, fabsf(u.z));
      a.w = fmaxf(a.w, fabsf(u.w));
    }
    ((float4*)part)[(size_t)slab * 1024 + t] = a;
    return;
  }

  // ---- activation: one 16-row tile per block, one wave per row ----
  const int tile = blockIdx.x - 32;
  const int row = t >> 6;  // 0..15 == wave id
  const int j = t & 63;    // lane
  const float4* xr = (const float4*)X + ((size_t)tile * 16 + row) * 1024;

  // read the row once; each lane holds 16 consecutive floats per u-group
  float4 v[4][4];
  float am = 0.f;
#pragma unroll
  for (int u = 0; u < 4; ++u)
#pragma unroll
    for (int c = 0; c < 4; ++c) {
      v[u][c] = xr[(u * 64 + j) * 4 + c];
      am = fmaxf(am, fmaxf(fmaxf(fabsf(v[u][c].x), fabsf(v[u][c].y)),
                           fmaxf(fabsf(v[u][c].z), fabsf(v[u][c].w))));
    }
  // wave == row: full 64-lane reduce gives the row amax
#pragma unroll
  for (int off = 32; off > 0; off >>= 1)
    am = fmaxf(am, __shfl_down(am, off));
  am = __shfl(am, 0);  // broadcast row amax to all lanes
  const float scale = fmaxf(am, 1e-6f) / 127.0f;  // matches ref
  if (j == 0) sx[tile * 16 + row] = scale;
  const float inv = 1.0f / scale;

  // quantize from registers; R2 tile layout: [ks256][row16][16B]
  signed char* tb = At + (size_t)tile * 65536 + row * 16;
#pragma unroll
  for (int u = 0; u < 4; ++u) {
    unsigned int d[4];
#pragma unroll
    for (int c = 0; c < 4; ++c) {
      int q0 = (int)fminf(fmaxf(rintf(v[u][c].x * inv), -127.f), 127.f);
      int q1 = (int)fminf(fmaxf(rintf(v[u][c].y * inv), -127.f), 127.f);
      int q2 = (int)fminf(fmaxf(rintf(v[u][c].z * inv), -127.f), 127.f);
      int q3 = (int)fminf(fmaxf(rintf(v[u][c].w * inv), -127.f), 127.f);
      d[c] = (q0 & 255) | ((q1 & 255) << 8) | ((q2 & 255) << 16) | (q3 << 24);
    }
    v4i w = {(int)d[0], (int)d[1], (int)d[2], (int)d[3]};
    *(v4i*)(tb + (u * 64 + j) * 256) = w;  // 16B k-slice s = u*64+j
  }
}

// ---------------- weight quant (+ inline scale combine) into Bt (R2 layout) ----
__global__ void wk_quant(const float* __restrict__ W,
                         const float* __restrict__ part,
                         signed char* __restrict__ Bt,
                         float* __restrict__ sk) {
  const int bx = blockIdx.x;
  const int f0 = (bx & 63) * 64;
  const int d0 = (bx >> 6) * 64;
  const int t = threadIdx.x;
  const int fl4 = t & 15;
  const int dl0 = t >> 4;
  __shared__ __align__(16) signed char tile[64 * 80];
  __shared__ float sl_inv[64];

  // issue the big W loads first; the scale-combine hides under them
  float4 wv[4];
#pragma unroll
  for (int c = 0; c < 4; ++c) {
    const int dl = c * 16 + dl0;
    wv[c] = ((const float4*)W)[(size_t)(d0 + dl) * 1024 + (f0 >> 2) + fl4];
  }
  if (t < 64) {
    const int f = f0 + t;
    float m = 0.f;
#pragma unroll
    for (int s = 0; s < 32; ++s) m = fmaxf(m, part[(size_t)s * 4096 + f]);
    const float scale = fmaxf(m, 1e-6f) / 127.0f;
    if (bx < 64) sk[f] = scale;  // d0==0 blocks publish sk exactly once
    sl_inv[t] = 1.0f / scale;
  }
  __syncthreads();
  const float4 inv4 = *(const float4*)&sl_inv[fl4 * 4];
#pragma unroll
  for (int c = 0; c < 4; ++c) {
    const int dl = c * 16 + dl0;
    tile[(fl4 * 4 + 0) * 80 + dl] =
        (signed char)(int)fminf(fmaxf(rintf(wv[c].x * inv4.x), -127.f), 127.f);
    tile[(fl4 * 4 + 1) * 80 + dl] =
        (signed char)(int)fminf(fmaxf(rintf(wv[c].y * inv4.y), -127.f), 127.f);
    tile[(fl4 * 4 + 2) * 80 + dl] =
        (signed char)(int)fminf(fmaxf(rintf(wv[c].z * inv4.z), -127.f), 127.f);
    tile[(fl4 * 4 + 3) * 80 + dl] =
        (signed char)(int)fminf(fmaxf(rintf(wv[c].w * inv4.w), -127.f), 127.f);
  }
  __syncthreads();
  const int frow = t >> 2;
  const int ksl = t & 3;
  v4i w = *(const v4i*)&tile[frow * 80 + ksl * 16];
  const int f = f0 + frow;
  signed char* dst = Bt + (size_t)(f >> 4) * 65536 + ((d0 >> 4) + ksl) * 256 +
                     (f & 15) * 16;
  *(v4i*)dst = w;
}

// ---------------- int8 GEMM: exact R2 kernel ----------------
__global__ __launch_bounds__(256, 2) void gemm_i8(
    const signed char* __restrict__ At, const signed char* __restrict__ Bt,
    const float* __restrict__ sx, const float* __restrict__ sk,
    float* __restrict__ C) {
  const int n0 = blockIdx.x * 128;
  const int m0 = blockIdx.y * 128;
  const int t = threadIdx.x;
  const int lane = t & 63;
  const int wave = t >> 6;
  const int wm = (wave >> 1) * 64;  // wave's 64x64 sub-tile
  const int wn = (wave & 1) * 64;
  const int lrow = lane & 15;
  const int lq = lane >> 4;

  __shared__ __align__(16) signed char lds[32768];
  signed char* lA = lds;
  signed char* lB = lds + 16384;

  v4i acc[4][4];
#pragma unroll
  for (int i = 0; i < 4; ++i)
#pragma unroll
    for (int j = 0; j < 4; ++j) acc[i][j] = (v4i){0, 0, 0, 0};

  const signed char* Abase = At + (size_t)(m0 >> 4) * 65536;
  const signed char* Bbase = Bt + (size_t)(n0 >> 4) * 65536;

  // fragment read bases: addr = mt_i*2048 + s*1024 + lane*16 (contiguous)
  const int la = ((wave >> 1) * 4) * 2048 + lane * 16;
  const int lb = ((wave & 1) * 4) * 2048 + lane * 16;

  for (int kb = 0; kb < K_DIM; kb += 128) {
    const int kofs = kb * 16;  // (kb/16)*256 bytes into each tile-row
    // stage 16KB A + 16KB B: every wave-instr reads 1KB contiguous,
    // MONOTONE lane->address (identity copy of the fragment-tiled layout)
#pragma unroll
    for (int j = 0; j < 4; ++j) {
      const int c = j * 256 + t;
      const int mt_i = c >> 7;
      const int inner = c & 127;
      __builtin_amdgcn_global_load_lds(
          (g_void_t*)(Abase + (size_t)mt_i * 65536 + kofs + inner * 16),
          (lds_void_t*)(lA + c * 16), 16, 0, 0);
      __builtin_amdgcn_global_load_lds(
          (g_void_t*)(Bbase + (size_t)mt_i * 65536 + kofs + inner * 16),
          (lds_void_t*)(lB + c * 16), 16, 0, 0);
    }
    __syncthreads();
#pragma unroll
    for (int s = 0; s < 2; ++s) {  // two K=64 steps per staging round
      v4i af[4], bf[4];
#pragma unroll
      for (int i = 0; i < 4; ++i) af[i] = *(const v4i*)(lA + la + i * 2048 + s * 1024);
#pragma unroll
      for (int i = 0; i < 4; ++i) bf[i] = *(const v4i*)(lB + lb + i * 2048 + s * 1024);
#pragma unroll
      for (int mi = 0; mi < 4; ++mi)
#pragma unroll
        for (int ni = 0; ni < 4; ++ni)
          acc[mi][ni] =
              __builtin_amdgcn_mfma_i32_16x16x64_i8(af[mi], bf[ni], acc[mi][ni], 0, 0, 0);
    }
    __syncthreads();
  }

  // epilogue: C/D layout col=lane&15, row=(lane>>4)*4+reg
#pragma unroll
  for (int mi = 0; mi < 4; ++mi) {
#pragma unroll
    for (int ni = 0; ni < 4; ++ni) {
      const int gn = n0 + wn + ni * 16 + lrow;
      const float skv = sk[gn];
#pragma unroll
      for (int r = 0; r < 4; ++r) {
        const int gm = m0 + wm + mi * 16 + lq * 4 + r;
        C[(size_t)gm * N_DIM + gn] = (float)acc[mi][ni][r] * sx[gm] * skv;
      }
    }
  }
}

// ---------------- launch ----------------
extern "C" void kernel_launch(void* const* d_in, const int* in_sizes, int n_in,
                              void* d_out, int out_size, void* d_ws, size_t ws_size,
                              hipStream_t stream) {
  const float* X = (const float*)d_in[0];  // [4,2048,4096] fp32
  const float* W = (const float*)d_in[1];  // [4096,4096] fp32
  float* out = (float*)d_out;              // [4,2048,4096] fp32
  char* ws = (char*)d_ws;

  signed char* At = (signed char*)ws;               // 32 MB  tiled A
  signed char* Bt = (signed char*)(ws + 33554432);  // 16 MB  tiled B
  float* sx = (float*)(ws + 50331648);              // 32 KB
  float* sk = (float*)(ws + 50364416);              // 16 KB
  float* part = (float*)(ws + 50380800);            // 512 KB (32 slabs x 4096)

  fused_prep<<<544, 1024, 0, stream>>>(X, W, At, sx, part);
  wk_quant<<<4096, 256, 0, stream>>>(W, part, Bt, sk);
  gemm_i8<<<dim3(N_DIM / 128, M_DIM / 128), 256, 0, stream>>>(At, Bt, sx, sk, out);
}

// Round 5
// 410.848 us; speedup vs baseline: 1.0798x; 1.0381x over previous
//
#include <hip/hip_runtime.h>

// out[b,s,f] = sx[b,s] * sk[f] * sum_d qx[b,s,d] * qk[d,f]
// Exact int32 accumulation via v_mfma_i32_16x16x64_i8.
//
// R7:
//  * GEMM geometry change ONLY (schedule = proven R2 2-barrier loop):
//    block 256x128, 4 waves, wave tile 128x64. Read:MFMA per wave per
//    K-tile(128B): 24 ds_read_b128 (~288cyc) vs 64 MFMA (~320cyc) ->
//    MFMA-bound (R2's 64x64 wave: 192 read vs 160 MFMA = LDS-read-bound).
//    LDS 48KB single-buffered, 2 blocks/CU; acc 8x4 v4i (AGPR).
//  * W-amax parallelism bug fixed: R6 used 32 blocks = 32 CUs at ~25GB/s/CU
//    = ~80us serial tail. Now 256 blocks (32 slabs x 8 col-groups), LDS
//    cross-wave combine; part stays [32][4096] so wk_quant is unchanged.
//  * X path unchanged from R6 (one X read, reg-held quant, full-line writes).

#define M_DIM 8192
#define K_DIM 4096
#define N_DIM 4096

typedef int v4i __attribute__((ext_vector_type(4)));
typedef __attribute__((address_space(3))) void lds_void_t;
typedef const __attribute__((address_space(1))) void g_void_t;

// ---------------- pass 1: W-slab amax partials (blocks 0..255) +
//                  fused act row-amax + quant (blocks 256..767) ----------------
__global__ __launch_bounds__(1024) void fused_prep(
    const float* __restrict__ X, const float* __restrict__ W,
    signed char* __restrict__ At, float* __restrict__ sx,
    float* __restrict__ part) {
  const int t = threadIdx.x;
  __shared__ float4 wred[1024];  // 16KB (W branch only)

  if (blockIdx.x < 256) {
    // 256 blocks = 32 slabs x 8 column-groups; each block: 128 rows x 512 cols
    const int slab = blockIdx.x >> 3;
    const int cg = blockIdx.x & 7;
    const int c4 = cg * 128 + (t & 127);  // float4 column 0..1023
    const int r0 = t >> 7;                // 0..7 row phase
    const float4* p = (const float4*)W + ((size_t)slab * 128 + r0) * 1024 + c4;
    float4 a = {0.f, 0.f, 0.f, 0.f};
#pragma unroll
    for (int i = 0; i < 16; ++i) {
      float4 u = p[(size_t)i * 8192];  // rows r0, r0+8, ... r0+120
      a.x = fmaxf(a.x, fabsf(u.x));
      a.y = fmaxf(a.y, fabsf(u.y));
      a.z = fmaxf(a.z, fabsf(u.z));
      a.w = fmaxf(a.w, fabsf(u.w));
    }
    wred[t] = a;
    __syncthreads();
    if (t < 128) {
      float4 m = wred[t];
#pragma unroll
      for (int j = 1; j < 8; ++j) {
        float4 u = wred[t + j * 128];
        m.x = fmaxf(m.x, u.x);
        m.y = fmaxf(m.y, u.y);
        m.z = fmaxf(m.z, u.z);
        m.w = fmaxf(m.w, u.w);
      }
      ((float4*)part)[(size_t)slab * 1024 + c4] = m;
    }
    return;
  }

  // ---- activation: one 16-row tile per block, one wave per row ----
  const int tile = blockIdx.x - 256;
  const int row = t >> 6;  // 0..15 == wave id
  const int j = t & 63;    // lane
  const float4* xr = (const float4*)X + ((size_t)tile * 16 + row) * 1024;

  float4 v[4][4];
  float am = 0.f;
#pragma unroll
  for (int u = 0; u < 4; ++u)
#pragma unroll
    for (int c = 0; c < 4; ++c) {
      v[u][c] = xr[(u * 64 + j) * 4 + c];
      am = fmaxf(am, fmaxf(fmaxf(fabsf(v[u][c].x), fabsf(v[u][c].y)),
                           fmaxf(fabsf(v[u][c].z), fabsf(v[u][c].w))));
    }
#pragma unroll
  for (int off = 32; off > 0; off >>= 1)
    am = fmaxf(am, __shfl_down(am, off));
  am = __shfl(am, 0);
  const float scale = fmaxf(am, 1e-6f) / 127.0f;  // matches ref
  if (j == 0) sx[tile * 16 + row] = scale;
  const float inv = 1.0f / scale;

  signed char* tb = At + (size_t)tile * 65536 + row * 16;
#pragma unroll
  for (int u = 0; u < 4; ++u) {
    unsigned int d[4];
#pragma unroll
    for (int c = 0; c < 4; ++c) {
      int q0 = (int)fminf(fmaxf(rintf(v[u][c].x * inv), -127.f), 127.f);
      int q1 = (int)fminf(fmaxf(rintf(v[u][c].y * inv), -127.f), 127.f);
      int q2 = (int)fminf(fmaxf(rintf(v[u][c].z * inv), -127.f), 127.f);
      int q3 = (int)fminf(fmaxf(rintf(v[u][c].w * inv), -127.f), 127.f);
      d[c] = (q0 & 255) | ((q1 & 255) << 8) | ((q2 & 255) << 16) | (q3 << 24);
    }
    v4i w = {(int)d[0], (int)d[1], (int)d[2], (int)d[3]};
    *(v4i*)(tb + (u * 64 + j) * 256) = w;  // [ks256][row16][16B]
  }
}

// ---------------- weight quant (+ inline scale combine) into Bt (R2 layout) ----
__global__ void wk_quant(const float* __restrict__ W,
                         const float* __restrict__ part,
                         signed char* __restrict__ Bt,
                         float* __restrict__ sk) {
  const int bx = blockIdx.x;
  const int f0 = (bx & 63) * 64;
  const int d0 = (bx >> 6) * 64;
  const int t = threadIdx.x;
  const int fl4 = t & 15;
  const int dl0 = t >> 4;
  __shared__ __align__(16) signed char tile[64 * 80];
  __shared__ float sl_inv[64];

  // issue the big W loads first; the scale-combine hides under them
  float4 wv[4];
#pragma unroll
  for (int c = 0; c < 4; ++c) {
    const int dl = c * 16 + dl0;
    wv[c] = ((const float4*)W)[(size_t)(d0 + dl) * 1024 + (f0 >> 2) + fl4];
  }
  if (t < 64) {
    const int f = f0 + t;
    float m = 0.f;
#pragma unroll
    for (int s = 0; s < 32; ++s) m = fmaxf(m, part[(size_t)s * 4096 + f]);
    const float scale = fmaxf(m, 1e-6f) / 127.0f;
    if (bx < 64) sk[f] = scale;  // d0==0 blocks publish sk exactly once
    sl_inv[t] = 1.0f / scale;
  }
  __syncthreads();
  const float4 inv4 = *(const float4*)&sl_inv[fl4 * 4];
#pragma unroll
  for (int c = 0; c < 4; ++c) {
    const int dl = c * 16 + dl0;
    tile[(fl4 * 4 + 0) * 80 + dl] =
        (signed char)(int)fminf(fmaxf(rintf(wv[c].x * inv4.x), -127.f), 127.f);
    tile[(fl4 * 4 + 1) * 80 + dl] =
        (signed char)(int)fminf(fmaxf(rintf(wv[c].y * inv4.y), -127.f), 127.f);
    tile[(fl4 * 4 + 2) * 80 + dl] =
        (signed char)(int)fminf(fmaxf(rintf(wv[c].z * inv4.z), -127.f), 127.f);
    tile[(fl4 * 4 + 3) * 80 + dl] =
        (signed char)(int)fminf(fmaxf(rintf(wv[c].w * inv4.w), -127.f), 127.f);
  }
  __syncthreads();
  const int frow = t >> 2;
  const int ksl = t & 3;
  v4i w = *(const v4i*)&tile[frow * 80 + ksl * 16];
  const int f = f0 + frow;
  signed char* dst = Bt + (size_t)(f >> 4) * 65536 + ((d0 >> 4) + ksl) * 256 +
                     (f & 15) * 16;
  *(v4i*)dst = w;
}

// ---------------- int8 GEMM: 256x128 block, 4 waves of 128x64, R2 schedule ----
__global__ __launch_bounds__(256, 2) void gemm_i8(
    const signed char* __restrict__ At, const signed char* __restrict__ Bt,
    const float* __restrict__ sx, const float* __restrict__ sk,
    float* __restrict__ C) {
  const int n0 = blockIdx.x * 128;
  const int m0 = blockIdx.y * 256;
  const int t = threadIdx.x;
  const int lane = t & 63;
  const int wave = t >> 6;           // 0..3
  const int wm = (wave >> 1) * 128;  // wave's 128x64 sub-tile
  const int wn = (wave & 1) * 64;
  const int lrow = lane & 15;
  const int lq = lane >> 4;

  __shared__ __align__(16) signed char lds[49152];  // 32KB A (16 tiles) + 16KB B (8)
  signed char* lA = lds;
  signed char* lB = lds + 32768;

  v4i acc[8][4];
#pragma unroll
  for (int i = 0; i < 8; ++i)
#pragma unroll
    for (int j = 0; j < 4; ++j) acc[i][j] = (v4i){0, 0, 0, 0};

  const signed char* Abase = At + (size_t)(m0 >> 4) * 65536;
  const signed char* Bbase = Bt + (size_t)(n0 >> 4) * 65536;

  // fragment read bases: addr = tile_i*2048 + s*1024 + lane*16 (contiguous)
  const int la = (wm >> 4) * 2048 + lane * 16;
  const int lb = (wn >> 4) * 2048 + lane * 16;

  for (int kb = 0; kb < K_DIM; kb += 128) {
    const int kofs = kb * 16;  // (kb/16)*256 bytes into each tile-row
    // stage 32KB A + 16KB B: every wave-instr reads 1KB contiguous,
    // MONOTONE lane->address (identity copy of the fragment-tiled layout)
#pragma unroll
    for (int j = 0; j < 8; ++j) {
      const int c = j * 256 + t;  // 0..2047
      __builtin_amdgcn_global_load_lds(
          (g_void_t*)(Abase + (size_t)(c >> 7) * 65536 + kofs + (c & 127) * 16),
          (lds_void_t*)(lA + c * 16), 16, 0, 0);
    }
#pragma unroll
    for (int j = 0; j < 4; ++j) {
      const int c = j * 256 + t;  // 0..1023
      __builtin_amdgcn_global_load_lds(
          (g_void_t*)(Bbase + (size_t)(c >> 7) * 65536 + kofs + (c & 127) * 16),
          (lds_void_t*)(lB + c * 16), 16, 0, 0);
    }
    __syncthreads();
#pragma unroll
    for (int s = 0; s < 2; ++s) {  // two K=64 steps per staging round
      v4i af[8], bf[4];
#pragma unroll
      for (int i = 0; i < 8; ++i) af[i] = *(const v4i*)(lA + la + i * 2048 + s * 1024);
#pragma unroll
      for (int i = 0; i < 4; ++i) bf[i] = *(const v4i*)(lB + lb + i * 2048 + s * 1024);
#pragma unroll
      for (int mi = 0; mi < 8; ++mi)
#pragma unroll
        for (int ni = 0; ni < 4; ++ni)
          acc[mi][ni] =
              __builtin_amdgcn_mfma_i32_16x16x64_i8(af[mi], bf[ni], acc[mi][ni], 0, 0, 0);
    }
    __syncthreads();
  }

  // epilogue: C/D layout col=lane&15, row=(lane>>4)*4+reg
#pragma unroll
  for (int mi = 0; mi < 8; ++mi) {
#pragma unroll
    for (int ni = 0; ni < 4; ++ni) {
      const int gn = n0 + wn + ni * 16 + lrow;
      const float skv = sk[gn];
#pragma unroll
      for (int r = 0; r < 4; ++r) {
        const int gm = m0 + wm + mi * 16 + lq * 4 + r;
        C[(size_t)gm * N_DIM + gn] = (float)acc[mi][ni][r] * sx[gm] * skv;
      }
    }
  }
}

// ---------------- launch ----------------
extern "C" void kernel_launch(void* const* d_in, const int* in_sizes, int n_in,
                              void* d_out, int out_size, void* d_ws, size_t ws_size,
                              hipStream_t stream) {
  const float* X = (const float*)d_in[0];  // [4,2048,4096] fp32
  const float* W = (const float*)d_in[1];  // [4096,4096] fp32
  float* out = (float*)d_out;              // [4,2048,4096] fp32
  char* ws = (char*)d_ws;

  signed char* At = (signed char*)ws;               // 32 MB  tiled A
  signed char* Bt = (signed char*)(ws + 33554432);  // 16 MB  tiled B
  float* sx = (float*)(ws + 50331648);              // 32 KB
  float* sk = (float*)(ws + 50364416);              // 16 KB
  float* part = (float*)(ws + 50380800);            // 512 KB (32 slabs x 4096)

  fused_prep<<<768, 1024, 0, stream>>>(X, W, At, sx, part);
  wk_quant<<<4096, 256, 0, stream>>>(W, part, Bt, sk);
  gemm_i8<<<dim3(N_DIM / 128, M_DIM / 256), 256, 0, stream>>>(At, Bt, sx, sk, out);
}